// Round 19
// baseline (387.051 us; speedup 1.0000x reference)
//
#include <hip/hip_runtime.h>
#include <hip/hip_bf16.h>
#include <math.h>

#define N_SKILLS 16

typedef __attribute__((ext_vector_type(8))) short s16x8;
typedef __attribute__((ext_vector_type(4))) float f32x4;

__device__ __forceinline__ unsigned short f2bf(float f) {
  unsigned int u = __float_as_uint(f);
  u += 0x7fffu + ((u >> 16) & 1u);
  return (unsigned short)(u >> 16);
}

#define GLDS(gsrc, ldst)                                                       \
  __builtin_amdgcn_global_load_lds(                                            \
      (const __attribute__((address_space(1))) unsigned int*)(gsrc),           \
      (__attribute__((address_space(3))) unsigned int*)(ldst), 16, 0, 0)

// ---------------------------------------------------------------------------
// Tile image layout (128 rows/cols x 64 k bf16 = 8192 shorts):
//   offset(row, klocal) = ((klocal>>3)*128 + row)*8 + (klocal&7)
// MFMA frag (16x16x32) read: lane(l15,kq), kk: 16B at ((kk*4+kq)*128+row)*8.
// ---------------------------------------------------------------------------

// route: grid 64 = b*4 + quarter. wA f32 [b][k*16+r]; wAt bf16 tile images;
// wBt bf16 [b][col*16+r] scaled by 1/16.
__global__ __launch_bounds__(256) void route_kernel(
    const float* __restrict__ skill_logits, const int* __restrict__ task_ids,
    const float* __restrict__ Askills, const float* __restrict__ Bskills,
    float* __restrict__ wA, unsigned short* __restrict__ wAt,
    unsigned short* __restrict__ wBt) {
  __shared__ float l[N_SKILLS];
  const int b = blockIdx.x >> 2, q = blockIdx.x & 3;
  const int tid = threadIdx.x;
  if (tid == 0) {
    int t = task_ids[b];
    float tmp[N_SKILLS];
    float s = 0.f;
    for (int k = 0; k < N_SKILLS; ++k) {
      float v = 1.f / (1.f + expf(-skill_logits[t * N_SKILLS + k]));
      tmp[k] = v;
      s += v;
    }
    float inv = 1.f / (s + 1e-12f);
    for (int k = 0; k < N_SKILLS; ++k) l[k] = tmp[k] * inv;
  }
  __syncthreads();
  for (int j = q * 4096 + tid; j < (q + 1) * 4096; j += 256) {
    float a = 0.f;
#pragma unroll
    for (int s = 0; s < 16; ++s) a += l[s] * Askills[s * 16384 + j];
    wA[b * 16384 + j] = a;
    const int k = j >> 4, r = j & 15;
    wAt[(b * 16 + (k >> 6)) * 1024 + (((k & 63) >> 3) * 16 + r) * 8 + (k & 7)] =
        f2bf(a);
    float v = 0.f;
#pragma unroll
    for (int s = 0; s < 16; ++s) v += l[s] * Bskills[s * 16384 + j];
    const int rr = j >> 10, col = j & 1023;
    wBt[b * 16384 + col * 16 + rr] = f2bf(v * 0.0625f);
  }
}

// aconv: input fp32 -> At bf16 tile images. Block = 64-row half of (mt,kt).
__global__ __launch_bounds__(256) void aconv_kernel(
    const float* __restrict__ A, unsigned short* __restrict__ At) {
  const int bx = blockIdx.x;  // tk*2 + rh
  const int rh = bx & 1;
  const int tk = bx >> 1;  // mt*16 + kt
  const int mt = tk >> 4, kt = tk & 15;
  const int tid = threadIdx.x;
  const int rowl = tid >> 2, kquad = tid & 3;
  const int rloc = rh * 64 + rowl;
  const float* src = A + (size_t)(mt * 128 + rloc) * 1024 + kt * 64 + kquad * 16;
  f32x4 v0 = *(const f32x4*)(src);
  f32x4 v1 = *(const f32x4*)(src + 4);
  f32x4 v2 = *(const f32x4*)(src + 8);
  f32x4 v3 = *(const f32x4*)(src + 12);
  s16x8 lo, hi;
#pragma unroll
  for (int j = 0; j < 4; ++j) {
    lo[j] = (short)f2bf(v0[j]);
    lo[j + 4] = (short)f2bf(v1[j]);
    hi[j] = (short)f2bf(v2[j]);
    hi[j + 4] = (short)f2bf(v3[j]);
  }
  unsigned short* dst = At + (size_t)tk * 8192 + ((kquad * 2) * 128 + rloc) * 8;
  *(s16x8*)&dst[0] = lo;
  *(s16x8*)&dst[1024] = hi;  // chunk kquad*2+1
}

// wconv: shared W -> Wt tile images (8 nt x 16 kt tiles of 128col x 64k).
__global__ __launch_bounds__(256) void wconv_kernel(
    const float* __restrict__ W, unsigned short* __restrict__ Wt) {
  const int bx = blockIdx.x;  // t*2 + ch
  const int ch = bx & 1;
  const int t = bx >> 1;  // nt*16 + kt
  const int nt = t >> 4, kt = t & 15;
  const int tid = threadIdx.x;
  const int c64 = tid >> 2, kq4 = tid & 3;
  const int col = ch * 64 + c64;
  const float* src = W + (size_t)(nt * 128 + col) * 1024 + kt * 64 + kq4 * 16;
  f32x4 v0 = *(const f32x4*)(src);
  f32x4 v1 = *(const f32x4*)(src + 4);
  f32x4 v2 = *(const f32x4*)(src + 8);
  f32x4 v3 = *(const f32x4*)(src + 12);
  s16x8 lo, hi;
#pragma unroll
  for (int j = 0; j < 4; ++j) {
    lo[j] = (short)f2bf(v0[j]);
    lo[j + 4] = (short)f2bf(v1[j]);
    hi[j] = (short)f2bf(v2[j]);
    hi[j + 4] = (short)f2bf(v3[j]);
  }
  unsigned short* dst = Wt + (size_t)t * 8192 + ((kq4 * 2) * 128 + col) * 8;
  *(s16x8*)&dst[0] = lo;
  *(s16x8*)&dst[1024] = hi;
}

// ---------------------------------------------------------------------------
// GEMM: C = A@W^T + (A@wA)@wBt + bias, with the rank-16 LoRA first stage
// FUSED into the K-loop: accL[mf] += mfma(CUR_Afrag, wAt_frag) per body
// (+8 MFMA/body, hidden in the latency-bound schedule; wAt is 32KB L1-hot).
// Epilogue transposes accL (D-layout) to A-frag layout via an LDS bounce
// (reusing Bs, free after the K-loop), then applies wBt (pre-scaled 1/16,
// K=32 zero-padded) + bias. Standalone lora1 kernel + its 128MB re-read
// are eliminated.
// Main-loop structure = PROVEN OPTIMUM (rounds 12/16/18): 128x128 tile,
// BK=64, 4 waves (2Mx2N); B via GLDS 32KB dbuf one tile ahead; A direct
// global->VGPR full-body register prefetch issued FIRST, pinned after the
// MFMA clusters; (256,3), VGPR ~80->~104.
// Do NOT: squeeze launch_bounds below VGPR need (r13/r14 spill/remat);
// move B to registers (r15: scheduler sinks prefetch at >128 VGPR live);
// quad-buffer B / drop barriers to 8 (r17: VGPR->112, occ->21%, -20%).
// ---------------------------------------------------------------------------
__global__ __launch_bounds__(256, 3) void gemm_kernel(
    const unsigned short* __restrict__ At, const unsigned short* __restrict__ Wt,
    const unsigned short* __restrict__ wBt, const unsigned short* __restrict__ wAt,
    const float* __restrict__ bias, float* __restrict__ C) {
  __shared__ __align__(16) unsigned short Bs[2][8192];

  const int orig = blockIdx.x;
  const int bid = (orig & 7) * 512 + (orig >> 3);  // XCD swizzle, 4096%8==0
  const int mt = bid >> 3;  // 0..511
  const int nt = bid & 7;   // 0..7
  const int batch = mt >> 5;
  const unsigned short* Ab = At + (size_t)mt * 16 * 8192;
  const unsigned short* Bb = Wt + (size_t)nt * 16 * 8192;
  const unsigned short* wAb = wAt + batch * 16 * 1024;

  const int tid = threadIdx.x, lane = tid & 63, wid = tid >> 6;
  const int wr = wid >> 1, wc = wid & 1;
  const int l15 = lane & 15, kq = lane >> 4;

  f32x4 acc[4][4] = {};
  f32x4 accL[4] = {};  // lora stage-1: rows wr*64+mf*16+kq*4+j, col r=l15
  s16x8 aP[2][4], aN[2][4];

#define STAGE_B(BUF, KT)                                                       \
  {                                                                            \
    const unsigned short* s_ = Bb + (size_t)(KT)*8192;                         \
    _Pragma("unroll") for (int c_ = 0; c_ < 4; ++c_) {                         \
      const int call_ = wid * 4 + c_;                                          \
      GLDS(s_ + call_ * 512 + lane * 8, &Bs[BUF][call_ * 512]);                \
    }                                                                          \
  }

#define LOAD_A8(DST, KT)                                                       \
  {                                                                            \
    const unsigned short* ap_ = Ab + (size_t)(KT)*8192;                        \
    _Pragma("unroll") for (int kk_ = 0; kk_ < 2; ++kk_)                        \
        _Pragma("unroll") for (int mf_ = 0; mf_ < 4; ++mf_)                    \
            DST[kk_][mf_] = *(const s16x8*)&ap_[((kk_ * 4 + kq) * 128 +        \
                                                 wr * 64 + mf_ * 16 + l15) *   \
                                                8];                            \
  }

#define PIN8(X)                                                                \
  asm volatile("" : "+v"(X[0][0]), "+v"(X[0][1]), "+v"(X[0][2]),               \
                    "+v"(X[0][3]), "+v"(X[1][0]), "+v"(X[1][1]),               \
                    "+v"(X[1][2]), "+v"(X[1][3]));

#define MFMA_CL(ABANK, BUF, KK)                                                \
  {                                                                            \
    s16x8 bfr_[4];                                                             \
    _Pragma("unroll") for (int nf_ = 0; nf_ < 4; ++nf_)                        \
        bfr_[nf_] = *(const s16x8*)&Bs[BUF][(((KK)*4 + kq) * 128 + wc * 64 +   \
                                             nf_ * 16 + l15) *                 \
                                            8];                                \
    _Pragma("unroll") for (int mf_ = 0; mf_ < 4; ++mf_)                        \
        _Pragma("unroll") for (int nf_ = 0; nf_ < 4; ++nf_)                    \
            acc[mf_][nf_] = __builtin_amdgcn_mfma_f32_16x16x32_bf16(           \
                ABANK[KK][mf_], bfr_[nf_], acc[mf_][nf_], 0, 0, 0);            \
  }

#define BODY(KT, BUF, CUR, NXT)                                                \
  {                                                                            \
    const int tn_ = ((KT) + 1 < 16) ? (KT) + 1 : 15;                           \
    const unsigned short* wb_ = wAb + (size_t)(KT)*1024;                       \
    s16x8 wf0_ = *(const s16x8*)&wb_[(kq * 16 + l15) * 8];                     \
    s16x8 wf1_ = *(const s16x8*)&wb_[((4 + kq) * 16 + l15) * 8];               \
    LOAD_A8(NXT, tn_);     /* issue first: leads VMEM FIFO */                  \
    STAGE_B((BUF) ^ 1, tn_);                                                   \
    MFMA_CL(CUR, BUF, 0);                                                      \
    MFMA_CL(CUR, BUF, 1);                                                      \
    _Pragma("unroll") for (int mf_ = 0; mf_ < 4; ++mf_) {                      \
      accL[mf_] = __builtin_amdgcn_mfma_f32_16x16x32_bf16(                     \
          CUR[0][mf_], wf0_, accL[mf_], 0, 0, 0);                              \
      accL[mf_] = __builtin_amdgcn_mfma_f32_16x16x32_bf16(                     \
          CUR[1][mf_], wf1_, accL[mf_], 0, 0, 0);                              \
    }                                                                          \
    PIN8(NXT);             /* use-point after MFMAs; blocks sinking */         \
    __syncthreads();                                                           \
  }

  LOAD_A8(aP, 0);
  STAGE_B(0, 0);
  __syncthreads();

#pragma unroll 1
  for (int kt = 0; kt < 16; kt += 2) {
    BODY(kt, 0, aP, aN);
    BODY(kt + 1, 1, aN, aP);
  }

  const int m0 = mt * 128, n0 = nt * 128;

  // --- LoRA epilogue ---
  // Transpose accL (row=kq*4+j, col r=l15) to A-frag layout (row=l15,
  // k=kq*8+j) via per-wave LDS region (Bs is dead after the K-loop).
  float* ldsf = (float*)&Bs[0][0];
  const int reg0 = wid * 1024;  // 4KB floats per wave
  __syncthreads();
#pragma unroll
  for (int mf = 0; mf < 4; ++mf)
#pragma unroll
    for (int j = 0; j < 4; ++j)
      ldsf[reg0 + mf * 256 + (kq * 4 + j) * 16 + l15] = accL[mf][j];
  __syncthreads();
  {
    s16x8 lafrag[4], wbfrag[4];
#pragma unroll
    for (int mf = 0; mf < 4; ++mf) {
      s16x8 v = {0, 0, 0, 0, 0, 0, 0, 0};
      if (kq < 2) {
#pragma unroll
        for (int j = 0; j < 8; ++j)
          v[j] = (short)f2bf(ldsf[reg0 + mf * 256 + l15 * 16 + kq * 8 + j]);
      }
      lafrag[mf] = v;
    }
#pragma unroll
    for (int nf = 0; nf < 4; ++nf) {
      s16x8 v = {0, 0, 0, 0, 0, 0, 0, 0};
      if (kq < 2)
        v = *(const s16x8*)&wBt[(size_t)batch * 16384 +
                                (n0 + wc * 64 + nf * 16 + l15) * 16 + kq * 8];
      wbfrag[nf] = v;
    }
#pragma unroll
    for (int mf = 0; mf < 4; ++mf)
#pragma unroll
      for (int nf = 0; nf < 4; ++nf)
        acc[mf][nf] = __builtin_amdgcn_mfma_f32_16x16x32_bf16(
            lafrag[mf], wbfrag[nf], acc[mf][nf], 0, 0, 0);
  }

  // bias + store
#pragma unroll
  for (int nf = 0; nf < 4; ++nf) {
    const int col = n0 + wc * 64 + nf * 16 + l15;
    const float bv = bias[col];
#pragma unroll
    for (int mf = 0; mf < 4; ++mf) {
      const int row = m0 + wr * 64 + mf * 16 + kq * 4;
#pragma unroll
      for (int j = 0; j < 4; ++j)
        C[(size_t)(row + j) * 1024 + col] = acc[mf][nf][j] + bv;
    }
  }
}

// ---------------------------------------------------------------------------
extern "C" void kernel_launch(void* const* d_in, const int* in_sizes, int n_in,
                              void* d_out, int out_size, void* d_ws,
                              size_t ws_size, hipStream_t stream) {
  const float* input = (const float*)d_in[0];
  const float* skill_logits = (const float*)d_in[1];
  const float* weight = (const float*)d_in[2];
  const float* bias = (const float*)d_in[3];
  const float* Askills = (const float*)d_in[4];
  const float* Bskills = (const float*)d_in[5];
  const int* task_ids = (const int*)d_in[6];

  float* wA = (float*)d_ws;                                    // 1 MB
  float* lora1 = wA + 262144;                                  // 4 MB (unused)
  unsigned short* wAt = (unsigned short*)(lora1 + 1048576);    // 512 KB
  unsigned short* wBt = wAt + 262144;                          // 512 KB
  unsigned short* Wt = wBt + 262144;                           // 2 MB
  unsigned short* At = Wt + 1048576;                           // 128 MB

  route_kernel<<<64, 256, 0, stream>>>(skill_logits, task_ids, Askills,
                                       Bskills, wA, wAt, wBt);
  wconv_kernel<<<256, 256, 0, stream>>>(weight, Wt);
  aconv_kernel<<<16384, 256, 0, stream>>>(input, At);
  gemm_kernel<<<4096, 256, 0, stream>>>(At, Wt, wBt, wAt, bias,
                                        (float*)d_out);
}

// Round 20
// 308.542 us; speedup vs baseline: 1.2545x; 1.2545x over previous
//
#include <hip/hip_runtime.h>
#include <hip/hip_bf16.h>
#include <math.h>

#define N_SKILLS 16

typedef __attribute__((ext_vector_type(8))) short s16x8;
typedef __attribute__((ext_vector_type(4))) float f32x4;

__device__ __forceinline__ unsigned short f2bf(float f) {
  unsigned int u = __float_as_uint(f);
  u += 0x7fffu + ((u >> 16) & 1u);
  return (unsigned short)(u >> 16);
}

#define GLDS(gsrc, ldst)                                                       \
  __builtin_amdgcn_global_load_lds(                                            \
      (const __attribute__((address_space(1))) unsigned int*)(gsrc),           \
      (__attribute__((address_space(3))) unsigned int*)(ldst), 16, 0, 0)

// ---------------------------------------------------------------------------
// Tile image layout (128 rows/cols x 64 k bf16 = 8192 shorts):
//   offset(row, klocal) = ((klocal>>3)*128 + row)*8 + (klocal&7)
// MFMA frag (16x16x32) read: lane(l15,kq), kk: 16B at ((kk*4+kq)*128+row)*8.
// ---------------------------------------------------------------------------

// route: grid 64 = b*4 + quarter. wA f32 [b][k*16+r]; wAt bf16 tile images;
// wBt bf16 [b][col*16+r] scaled by 1/16.
__global__ __launch_bounds__(256) void route_kernel(
    const float* __restrict__ skill_logits, const int* __restrict__ task_ids,
    const float* __restrict__ Askills, const float* __restrict__ Bskills,
    float* __restrict__ wA, unsigned short* __restrict__ wAt,
    unsigned short* __restrict__ wBt) {
  __shared__ float l[N_SKILLS];
  const int b = blockIdx.x >> 2, q = blockIdx.x & 3;
  const int tid = threadIdx.x;
  if (tid == 0) {
    int t = task_ids[b];
    float tmp[N_SKILLS];
    float s = 0.f;
    for (int k = 0; k < N_SKILLS; ++k) {
      float v = 1.f / (1.f + expf(-skill_logits[t * N_SKILLS + k]));
      tmp[k] = v;
      s += v;
    }
    float inv = 1.f / (s + 1e-12f);
    for (int k = 0; k < N_SKILLS; ++k) l[k] = tmp[k] * inv;
  }
  __syncthreads();
  for (int j = q * 4096 + tid; j < (q + 1) * 4096; j += 256) {
    float a = 0.f;
#pragma unroll
    for (int s = 0; s < 16; ++s) a += l[s] * Askills[s * 16384 + j];
    wA[b * 16384 + j] = a;
    const int k = j >> 4, r = j & 15;
    wAt[(b * 16 + (k >> 6)) * 1024 + (((k & 63) >> 3) * 16 + r) * 8 + (k & 7)] =
        f2bf(a);
    float v = 0.f;
#pragma unroll
    for (int s = 0; s < 16; ++s) v += l[s] * Bskills[s * 16384 + j];
    const int rr = j >> 10, col = j & 1023;
    wBt[b * 16384 + col * 16 + rr] = f2bf(v * 0.0625f);
  }
}

// aconv: input fp32 -> At bf16 tile images. Block = 64-row half of (mt,kt).
__global__ __launch_bounds__(256) void aconv_kernel(
    const float* __restrict__ A, unsigned short* __restrict__ At) {
  const int bx = blockIdx.x;  // tk*2 + rh
  const int rh = bx & 1;
  const int tk = bx >> 1;  // mt*16 + kt
  const int mt = tk >> 4, kt = tk & 15;
  const int tid = threadIdx.x;
  const int rowl = tid >> 2, kquad = tid & 3;
  const int rloc = rh * 64 + rowl;
  const float* src = A + (size_t)(mt * 128 + rloc) * 1024 + kt * 64 + kquad * 16;
  f32x4 v0 = *(const f32x4*)(src);
  f32x4 v1 = *(const f32x4*)(src + 4);
  f32x4 v2 = *(const f32x4*)(src + 8);
  f32x4 v3 = *(const f32x4*)(src + 12);
  s16x8 lo, hi;
#pragma unroll
  for (int j = 0; j < 4; ++j) {
    lo[j] = (short)f2bf(v0[j]);
    lo[j + 4] = (short)f2bf(v1[j]);
    hi[j] = (short)f2bf(v2[j]);
    hi[j + 4] = (short)f2bf(v3[j]);
  }
  unsigned short* dst = At + (size_t)tk * 8192 + ((kquad * 2) * 128 + rloc) * 8;
  *(s16x8*)&dst[0] = lo;
  *(s16x8*)&dst[1024] = hi;  // chunk kquad*2+1
}

// wconv: shared W -> Wt tile images (8 nt x 16 kt tiles of 128col x 64k).
__global__ __launch_bounds__(256) void wconv_kernel(
    const float* __restrict__ W, unsigned short* __restrict__ Wt) {
  const int bx = blockIdx.x;  // t*2 + ch
  const int ch = bx & 1;
  const int t = bx >> 1;  // nt*16 + kt
  const int nt = t >> 4, kt = t & 15;
  const int tid = threadIdx.x;
  const int c64 = tid >> 2, kq4 = tid & 3;
  const int col = ch * 64 + c64;
  const float* src = W + (size_t)(nt * 128 + col) * 1024 + kt * 64 + kq4 * 16;
  f32x4 v0 = *(const f32x4*)(src);
  f32x4 v1 = *(const f32x4*)(src + 4);
  f32x4 v2 = *(const f32x4*)(src + 8);
  f32x4 v3 = *(const f32x4*)(src + 12);
  s16x8 lo, hi;
#pragma unroll
  for (int j = 0; j < 4; ++j) {
    lo[j] = (short)f2bf(v0[j]);
    lo[j + 4] = (short)f2bf(v1[j]);
    hi[j] = (short)f2bf(v2[j]);
    hi[j + 4] = (short)f2bf(v3[j]);
  }
  unsigned short* dst = Wt + (size_t)t * 8192 + ((kq4 * 2) * 128 + col) * 8;
  *(s16x8*)&dst[0] = lo;
  *(s16x8*)&dst[1024] = hi;
}

// lora1 = A_bf16 @ wA (65536x1024 @ 1024x16), MFMA, no LDS, no barriers.
__global__ __launch_bounds__(256) void lora1_kernel(
    const unsigned short* __restrict__ At, const unsigned short* __restrict__ wAt,
    float* __restrict__ lora1) {
  const int mt = blockIdx.x;  // 0..511
  const int batch = mt >> 5;
  const int tid = threadIdx.x;
  const int lane = tid & 63, w = tid >> 6;
  const int l15 = lane & 15, kq = lane >> 4;
  f32x4 acc[2] = {};
  const unsigned short* Ab = At + (size_t)mt * 16 * 8192;
  const unsigned short* Wb = wAt + batch * 16 * 1024;
#pragma unroll 1
  for (int kt = 0; kt < 16; ++kt) {
    const unsigned short* at = Ab + kt * 8192;
    const unsigned short* wt = Wb + kt * 1024;
#pragma unroll
    for (int kk = 0; kk < 2; ++kk) {
      s16x8 bfrag = *(const s16x8*)&wt[((kk * 4 + kq) * 16 + l15) * 8];
#pragma unroll
      for (int mf = 0; mf < 2; ++mf) {
        s16x8 af = *(const s16x8*)&at[((kk * 4 + kq) * 128 + w * 32 + mf * 16 + l15) * 8];
        acc[mf] = __builtin_amdgcn_mfma_f32_16x16x32_bf16(af, bfrag, acc[mf], 0, 0, 0);
      }
    }
  }
#pragma unroll
  for (int mf = 0; mf < 2; ++mf) {
    const int row = mt * 128 + w * 32 + mf * 16 + kq * 4;
#pragma unroll
    for (int jj = 0; jj < 4; ++jj)
      lora1[(size_t)(row + jj) * 16 + l15] = acc[mf][jj];
  }
}

// ---------------------------------------------------------------------------
// GEMM: C = A@W^T + lora1@wBt + bias. 128x128 tile, BK=64, 4 waves (2Mx2N).
// B via GLDS 32KB dbuf (one tile ahead). A direct global->VGPR with FULL-BODY
// register prefetch: next iteration's 8 A-frags issued FIRST in the body
// (before GLDS, so they lead the VMEM FIFO), consumed next body; an opaque
// asm pin after the MFMA clusters prevents the compiler sinking/remat'ing
// the loads. Barrier vmcnt(0) drain lands after both MFMA clusters -> the
// A stream gets the same one-body latency cover as B.
// PROVEN OPTIMUM (rounds 12/16/18): 191us / 719TF, VGPR=80, (256,3).
// Do NOT: squeeze launch_bounds below VGPR need (r13/r14 spill/remat);
// move B to registers (r15: scheduler sinks prefetch at >128 VGPR live);
// quad-buffer B / drop barriers to 8 (r17: VGPR->112, occ->21%, -20%);
// fuse lora stage-1 into BODY (r19: prefetch demoted, FETCH+47MB, -100us).
// ---------------------------------------------------------------------------
__global__ __launch_bounds__(256, 3) void gemm_kernel(
    const unsigned short* __restrict__ At, const unsigned short* __restrict__ Wt,
    const unsigned short* __restrict__ wBt, const float* __restrict__ lora1,
    const float* __restrict__ bias, float* __restrict__ C) {
  __shared__ __align__(16) unsigned short Bs[2][8192];

  const int orig = blockIdx.x;
  const int bid = (orig & 7) * 512 + (orig >> 3);  // XCD swizzle, 4096%8==0
  const int mt = bid >> 3;  // 0..511
  const int nt = bid & 7;   // 0..7
  const int batch = mt >> 5;
  const unsigned short* Ab = At + (size_t)mt * 16 * 8192;
  const unsigned short* Bb = Wt + (size_t)nt * 16 * 8192;

  const int tid = threadIdx.x, lane = tid & 63, wid = tid >> 6;
  const int wr = wid >> 1, wc = wid & 1;
  const int l15 = lane & 15, kq = lane >> 4;

  f32x4 acc[4][4] = {};
  s16x8 aP[2][4], aN[2][4];

#define STAGE_B(BUF, KT)                                                       \
  {                                                                            \
    const unsigned short* s_ = Bb + (size_t)(KT)*8192;                         \
    _Pragma("unroll") for (int c_ = 0; c_ < 4; ++c_) {                         \
      const int call_ = wid * 4 + c_;                                          \
      GLDS(s_ + call_ * 512 + lane * 8, &Bs[BUF][call_ * 512]);                \
    }                                                                          \
  }

#define LOAD_A8(DST, KT)                                                       \
  {                                                                            \
    const unsigned short* ap_ = Ab + (size_t)(KT)*8192;                        \
    _Pragma("unroll") for (int kk_ = 0; kk_ < 2; ++kk_)                        \
        _Pragma("unroll") for (int mf_ = 0; mf_ < 4; ++mf_)                    \
            DST[kk_][mf_] = *(const s16x8*)&ap_[((kk_ * 4 + kq) * 128 +        \
                                                 wr * 64 + mf_ * 16 + l15) *   \
                                                8];                            \
  }

#define PIN8(X)                                                                \
  asm volatile("" : "+v"(X[0][0]), "+v"(X[0][1]), "+v"(X[0][2]),               \
                    "+v"(X[0][3]), "+v"(X[1][0]), "+v"(X[1][1]),               \
                    "+v"(X[1][2]), "+v"(X[1][3]));

#define MFMA_CL(ABANK, BUF, KK)                                                \
  {                                                                            \
    s16x8 bfr_[4];                                                             \
    _Pragma("unroll") for (int nf_ = 0; nf_ < 4; ++nf_)                        \
        bfr_[nf_] = *(const s16x8*)&Bs[BUF][(((KK)*4 + kq) * 128 + wc * 64 +   \
                                             nf_ * 16 + l15) *                 \
                                            8];                                \
    _Pragma("unroll") for (int mf_ = 0; mf_ < 4; ++mf_)                        \
        _Pragma("unroll") for (int nf_ = 0; nf_ < 4; ++nf_)                    \
            acc[mf_][nf_] = __builtin_amdgcn_mfma_f32_16x16x32_bf16(           \
                ABANK[KK][mf_], bfr_[nf_], acc[mf_][nf_], 0, 0, 0);            \
  }

#define BODY(KT, BUF, CUR, NXT)                                                \
  {                                                                            \
    const int tn_ = ((KT) + 1 < 16) ? (KT) + 1 : 15;                           \
    LOAD_A8(NXT, tn_);     /* issue first: leads VMEM FIFO */                  \
    STAGE_B((BUF) ^ 1, tn_);                                                   \
    MFMA_CL(CUR, BUF, 0);                                                      \
    MFMA_CL(CUR, BUF, 1);                                                      \
    PIN8(NXT);             /* use-point after MFMAs; blocks sinking */         \
    __syncthreads();                                                           \
  }

  LOAD_A8(aP, 0);
  STAGE_B(0, 0);
  __syncthreads();

#pragma unroll 1
  for (int kt = 0; kt < 16; kt += 2) {
    BODY(kt, 0, aP, aN);
    BODY(kt + 1, 1, aN, aP);
  }

  const int m0 = mt * 128, n0 = nt * 128;

  // LoRA epilogue: acc += bf16(lora1) @ wBt  (K=32, rows 16..31 zero-padded).
  {
    s16x8 lafrag[4], wbfrag[4];
#pragma unroll
    for (int mf = 0; mf < 4; ++mf) {
      s16x8 v = {0, 0, 0, 0, 0, 0, 0, 0};
      if (kq < 2) {
        const float* lp = lora1 + (size_t)(m0 + wr * 64 + mf * 16 + l15) * 16 + kq * 8;
        f32x4 x0 = *(const f32x4*)lp;
        f32x4 x1 = *(const f32x4*)(lp + 4);
#pragma unroll
        for (int j = 0; j < 4; ++j) {
          v[j] = (short)f2bf(x0[j]);
          v[j + 4] = (short)f2bf(x1[j]);
        }
      }
      lafrag[mf] = v;
    }
#pragma unroll
    for (int nf = 0; nf < 4; ++nf) {
      s16x8 v = {0, 0, 0, 0, 0, 0, 0, 0};
      if (kq < 2)
        v = *(const s16x8*)&wBt[(size_t)batch * 16384 +
                                (n0 + wc * 64 + nf * 16 + l15) * 16 + kq * 8];
      wbfrag[nf] = v;
    }
#pragma unroll
    for (int mf = 0; mf < 4; ++mf)
#pragma unroll
      for (int nf = 0; nf < 4; ++nf)
        acc[mf][nf] = __builtin_amdgcn_mfma_f32_16x16x32_bf16(
            lafrag[mf], wbfrag[nf], acc[mf][nf], 0, 0, 0);
  }

  // bias + store
#pragma unroll
  for (int nf = 0; nf < 4; ++nf) {
    const int col = n0 + wc * 64 + nf * 16 + l15;
    const float bv = bias[col];
#pragma unroll
    for (int mf = 0; mf < 4; ++mf) {
      const int row = m0 + wr * 64 + mf * 16 + kq * 4;
#pragma unroll
      for (int j = 0; j < 4; ++j)
        C[(size_t)(row + j) * 1024 + col] = acc[mf][nf][j] + bv;
    }
  }
}

// ---------------------------------------------------------------------------
extern "C" void kernel_launch(void* const* d_in, const int* in_sizes, int n_in,
                              void* d_out, int out_size, void* d_ws,
                              size_t ws_size, hipStream_t stream) {
  const float* input = (const float*)d_in[0];
  const float* skill_logits = (const float*)d_in[1];
  const float* weight = (const float*)d_in[2];
  const float* bias = (const float*)d_in[3];
  const float* Askills = (const float*)d_in[4];
  const float* Bskills = (const float*)d_in[5];
  const int* task_ids = (const int*)d_in[6];

  float* wA = (float*)d_ws;                                    // 1 MB
  float* lora1 = wA + 262144;                                  // 4 MB
  unsigned short* wAt = (unsigned short*)(lora1 + 1048576);    // 512 KB
  unsigned short* wBt = wAt + 262144;                          // 512 KB
  unsigned short* Wt = wBt + 262144;                           // 2 MB
  unsigned short* At = Wt + 1048576;                           // 128 MB

  route_kernel<<<64, 256, 0, stream>>>(skill_logits, task_ids, Askills,
                                       Bskills, wA, wAt, wBt);
  wconv_kernel<<<256, 256, 0, stream>>>(weight, Wt);
  aconv_kernel<<<16384, 256, 0, stream>>>(input, At);
  lora1_kernel<<<512, 256, 0, stream>>>(At, wAt, lora1);
  gemm_kernel<<<4096, 256, 0, stream>>>(At, Wt, wBt, lora1, bias,
                                        (float*)d_out);
}